// Round 2
// baseline (805.908 us; speedup 1.0000x reference)
//
#include <hip/hip_runtime.h>

// StealNMSLoss for MI355X (gfx950).  Round 7: dispatch consolidation.
//
// Round 6 post-mortem: patch-gather rewrite (LDS ops 85->19/thread) was
// NEUTRAL (250.4 -> 247.9 us).  Modeled kernel costs (dir ~20us, nms ~30us
// vs 25us HBM floor) sum to far less than dur_us=248; the only >77us
// dispatches in the trace are harness 512-MiB poison fills already at 86%
// HBM peak.  Conclusion: timed window is dominated by fixed harness cost +
// dispatch overhead.  Remaining owned lever: dispatch count.
//
// Round 7 changes (numerics of per-pixel math untouched):
//  - hipMemsetAsync(slots) removed; dir_kernel block (0,0,0) zeroes the 256
//    slots + done-counter (stream order guarantees visibility before any
//    nms_sum atomicAdd).
//  - reduce_ws_kernel removed; the LAST nms_sum block (device-scope
//    fetch_add on a done-counter, acquire loads of slots) does the final
//    256->1 reduction and writes d_out.  4 dispatches -> 2.
//  - per-pixel column-validity hoisted out of the row loop (4x not 16x).
//
// Phase 1 (dir_kernel): per (b,pixel) compute 2-bit NMS direction for ALL 16
//   classes from the label map only; pack into u32/pixel dir-map in d_ws.
// Phase 2 (nms_sum_kernel): per (b,c,tile) stage exp(pred) tile in LDS; each
//   thread owns a 4-col x 4-row pixel patch; rolling 4-row register window,
//   14x ds_read_b128 per 16 pixels; per-pixel denominator = 6 cndmask + 3
//   adds; acc += num * rcp(den).
//
// Math notes (bit-exact vs reference, rounds 1-6):
//  - Composed Sobel-of-Sobel on one-hot mask = exact integer stencils /64:
//      gxx = [1,4,6,4,1]_h (x) [1,0,-2,0,1]_w / 64
//      gxy = [-1,-2,0,2,1]_h (x) [-1,-2,0,2,1]_w / 64
//      gyy = [1,0,-2,0,1]_h (x) [1,4,6,4,1]_w / 64
//  - dir classification in exact integers (|gxx|,|gyy| <= 32): tan(pi/10)
//    lies between Farey neighbors 10/31, 1/3 -> t1 = (100|gyy| > 33|gxx|);
//    tan(3pi/10) between 11/8, 40/29 -> t2 = (1000|gyy| > 1377|gxx|).
//    gxx==0 (den=eps>0) and gyy==0 cases verified to match the float path.
//    ng = (gyy<0) ^ (gxy>0) ^ (gxx<0).
//  - Only interior [2,H-2) x [2,W-2) contributes; dirs 1,3 share the
//    anti-diagonal denominator (same offset set).
//  - Gather element positions relative to pixel (row r, col x), ascending
//    offset order and add association as rounds 5-6:
//      dir0 (horiz): (r,x-2) (r,x-1) (r,x) (r,x+1)
//      dir2 (vert):  (r-2,x) (r-1,x) (r,x) (r+1,x)
//      dir1/3:       (r-2,x+1) (r-1,x) (r,x-1) (r+1,x-2)
//    den = ((g0+g1)+g2)+g3, acc += nn * rcp(den) — unchanged numerics.

#define Bn 4
#define Cn 16
#define Hn 512
#define Wn 1024

typedef unsigned long long u64;
typedef unsigned int u32;
typedef float f4u __attribute__((ext_vector_type(4), aligned(4)));
typedef int   i4u __attribute__((ext_vector_type(4), aligned(4)));

static __device__ __forceinline__ float fast_rcp(float x) {
#if __has_builtin(__builtin_amdgcn_rcpf)
  return __builtin_amdgcn_rcpf(x);
#else
  return 1.0f / x;
#endif
}

// ======================= Phase 1: direction map =======================
// Tile 128w x 8h, 256 threads = 32 tcols x 8 rows; thread owns 4 adjacent
// pixels in one row.  SWAR over 8 pixel-byte-lanes per u64.

#define P1TW 128
#define P1TH 8
#define P1LW 132
#define P1LH 12

__global__ __launch_bounds__(256)
void dir_kernel(const int* __restrict__ labels, u32* __restrict__ dirs,
                float* __restrict__ slots, u32* __restrict__ done_counter)
{
  __shared__ unsigned char labt[P1LH][P1LW];

  const int w0 = blockIdx.x * P1TW;
  const int h0 = blockIdx.y * P1TH;
  const int b  = blockIdx.z;
  const int tid = threadIdx.x;

  // zero the reduction slots + done counter (replaces hipMemsetAsync);
  // stream order (dir completes before nms starts) guarantees visibility.
  if (blockIdx.x == 0 && blockIdx.y == 0 && blockIdx.z == 0) {
    slots[tid] = 0.f;
    if (tid == 0) *done_counter = 0u;
  }

  const int* lbase = labels + (size_t)b * (Hn*Wn);
  const bool interior = (h0 >= 2) && (h0 + P1TH + 2 <= Hn) &&
                        (w0 >= 2) && (w0 + P1TW + 2 <= Wn);
  if (interior) {
    const int* lb = lbase + (size_t)(h0-2)*Wn + (w0-2);
    for (int i = tid; i < P1LH*33; i += 256) {
      int row = i / 33, c4 = (i - row*33) * 4;
      i4u L = *(const i4u*)(lb + row*Wn + c4);
      *(u32*)&labt[row][c4] =
          (u32)L.x | ((u32)L.y << 8) | ((u32)L.z << 16) | ((u32)L.w << 24);
    }
  } else {
    for (int i = tid; i < P1LH*33; i += 256) {
      int row = i / 33, c4 = (i - row*33) * 4;
      int gh = min(max(h0-2+row, 0), Hn-1);
      const int* lr = lbase + gh*Wn;
      u32 v = 0;
      #pragma unroll
      for (int k = 0; k < 4; ++k) {
        int gw = min(max(w0-2+c4+k, 0), Wn-1);
        v |= (u32)(lr[gw] & 0xff) << (8*k);
      }
      *(u32*)&labt[row][c4] = v;
    }
  }
  __syncthreads();

  const int tcol = tid & 31;
  const int trow = tid >> 5;

  // 5 window rows x 8 byte-cols (pixels at bytes 2..5 <-> gw = w0+4*tcol+0..3)
  u64 W[5];
  #pragma unroll
  for (int r = 0; r < 5; ++r) {
    const u32* lp = (const u32*)&labt[trow + r][0];
    u64 lo = lp[tcol];
    u64 hi = lp[tcol + 1];
    W[r] = lo | (hi << 32);
  }

  u32 pack[4] = {0u, 0u, 0u, 0u};

  #pragma unroll 1
  for (int c = 0; c < 16; ++c) {
    const u64 crep = 0x0101010101010101ULL * (u32)c;
    u64 m[5];
    #pragma unroll
    for (int r = 0; r < 5; ++r) {
      u64 x = W[r] ^ crep;
      m[r] = ((0x8080808080808080ULL - x) & 0x8080808080808080ULL) >> 7;
    }
    // vertical packed sums (pixel-byte lanes), all biases byte-safe:
    u64 t  = m[1] + m[3];
    u64 VA = m[0] + m[4] + (t << 2) + (m[2] << 2) + (m[2] << 1);          // [0,16]
    u64 VB = ((m[3] << 1) + m[4] + 0x0303030303030303ULL)
             - (m[0] + (m[1] << 1));                                       // [0,6]
    u64 VC = (m[0] + m[4] + 0x0202020202020202ULL) - (m[2] << 1);          // [0,4]
    // horizontal combine; result bytes k=0..3 = this thread's 4 pixels
    u64 gxxp = (VA + (VA >> 32) + 0x4040404040404040ULL) - ((VA >> 16) << 1);
    u64 q1   = (VC >> 8) + (VC >> 24);
    u64 w16  = VC >> 16;
    u64 gyyp = (VC + (VC >> 32)) + (q1 << 2) + (w16 << 2) + (w16 << 1);
    u64 gxyp = (((VB >> 24) << 1) + (VB >> 32) + 0x2020202020202020ULL)
             - (VB + ((VB >> 8) << 1));

    u32 gxxl = (u32)gxxp, gyyl = (u32)gyyp, gxyl = (u32)gxyp;
    #pragma unroll
    for (int k = 0; k < 4; ++k) {
      int gxx = (int)((gxxl >> (8*k)) & 0xffu) - 64;   // [-32,32]
      int gyy = (int)((gyyl >> (8*k)) & 0xffu) - 32;   // [-32,32]
      int gxyb = (int)((gxyl >> (8*k)) & 0xffu);       // >32 <=> gxy>0
      int ax = gxx < 0 ? -gxx : gxx;
      int ay = gyy < 0 ? -gyy : gyy;
      // __mul24: full-rate v_mul_u32_u24 (v_mul_lo_u32 is quarter-rate)
      int t1 = (__mul24(ay, 100)  > __mul24(ax, 33))   ? 1 : 0;
      int t2 = (__mul24(ay, 1000) > __mul24(ax, 1377)) ? 1 : 0;
      int rb = t1 + t2;
      bool ng = ((gyy < 0) != (gxyb > 32)) != (gxx < 0);
      int dir = ng ? ((rb == 2) ? 3 : 0) : rb;
      pack[k] |= (u32)dir << (2*c);
    }
  }

  const int gh = h0 + trow;
  u32* drow = dirs + ((size_t)b*Hn + gh)*Wn + (w0 + 4*tcol);
  *(uint4*)drow = make_uint4(pack[0], pack[1], pack[2], pack[3]);
}

// ======================= Phase 2: exp / denom sum =======================

#define TW 128
#define TH 32
#define LW 132
#define LH 36
#define NT 256
#define NMS_NBLK ((Wn/TW)*(Hn/TH)*(Bn*Cn))   // 8*16*64 = 8192

__global__ __launch_bounds__(NT)
void nms_sum_kernel(const float* __restrict__ pred,
                    const u32* __restrict__ dirs,
                    float* __restrict__ slots,
                    u32* __restrict__ done_counter,
                    float* __restrict__ out)
{
  __shared__ float ext[LH*LW];
  __shared__ float wsum[NT/64];
  __shared__ int lastFlag;

  const int w0 = blockIdx.x * TW;
  const int h0 = blockIdx.y * TH;
  const int bz = blockIdx.z;
  const int b  = bz >> 4;
  const int c  = bz & 15;
  const int tid = threadIdx.x;

  // compute-phase mapping: 256 threads = 8 row-groups x 32 col-groups;
  // thread owns a 4-col x 4-row pixel patch.
  const int tc  = tid & 31;
  const int rg  = tid >> 5;
  const int x0  = 4*tc;         // tile col of patch left edge
  const int r0  = 4*rg;         // tile row of patch top edge
  const int gw0 = w0 + x0;
  const int gh0 = h0 + r0;

  // ---- prefetch this thread's 16 dir words (issued before the barrier;
  //      dirs plane is 8 MB, reused by 16 class-blocks -> L2/L3 hits) ----
  const u32* dbase = dirs + (size_t)b*Hn*Wn + (size_t)gh0*Wn + gw0;
  const uint4 dq0 = *(const uint4*)(dbase);
  const uint4 dq1 = *(const uint4*)(dbase + Wn);
  const uint4 dq2 = *(const uint4*)(dbase + 2*(size_t)Wn);
  const uint4 dq3 = *(const uint4*)(dbase + 3*(size_t)Wn);

  // ---- stage exp tile ----
  const float* plane = pred + (size_t)(b*Cn + c) * (size_t)(Hn*Wn);
  const bool interior = (h0 >= 2) && (h0 + TH + 2 <= Hn) &&
                        (w0 >= 2) && (w0 + TW + 2 <= Wn);
  if (interior) {
    const float* pb = plane + (size_t)(h0-2)*Wn + (w0-2);
    for (int i = tid; i < LH*33; i += NT) {
      int row = i / 33, c4 = (i - row*33) * 4;
      f4u p = *(const f4u*)(pb + row*Wn + c4);
      float4 e;
      e.x = __expf(p.x); e.y = __expf(p.y); e.z = __expf(p.z); e.w = __expf(p.w);
      *(float4*)&ext[row*LW + c4] = e;
    }
  } else {
    for (int i = tid; i < LH*(LW/2); i += NT) {
      int row = i / (LW/2);
      int col = (i - row*(LW/2)) * 2;
      int gh = min(max(h0-2+row, 0), Hn-1);
      int ga = min(max(w0-2+col,   0), Wn-1);
      int gb = min(max(w0-1+col,   0), Wn-1);
      const float* prow = plane + gh*Wn;
      *(float2*)&ext[row*LW+col] = make_float2(__expf(prow[ga]), __expf(prow[gb]));
    }
  }
  __syncthreads();

  const u32 sh = 2u * (u32)c;

  // per-thread column validity, hoisted out of the row loop
  const bool wvm[4] = { (gw0+0 >= 2) && (gw0+0 < Wn-2),
                        (gw0+1 >= 2) && (gw0+1 < Wn-2),
                        (gw0+2 >= 2) && (gw0+2 < Wn-2),
                        (gw0+3 >= 2) && (gw0+3 < Wn-2) };

  // rolling 4-row register window: each row covers cols x0-2 .. x0+5.
  // LDS element index of (tile row t, col x0-2) = (t+2)*LW + x0 (16B-aligned).
  float p0[8], p1[8], p2[8], p3[8];

#define LDROW(P, TR) { const int _a = ((TR)+2)*LW + x0;                       \
    const f4u _lo = *(const f4u*)&ext[_a];                                    \
    const f4u _hi = *(const f4u*)&ext[_a + 4];                                \
    P[0]=_lo.x; P[1]=_lo.y; P[2]=_lo.z; P[3]=_lo.w;                           \
    P[4]=_hi.x; P[5]=_hi.y; P[6]=_hi.z; P[7]=_hi.w; }

  float acc = 0.f;

  // A = row r-2, B = row r-1, Cc = row r (pixel row), D = row r+1.
  // Pixel i sits at window element i+2.  Selects keep the ascending
  // offset order and add association exactly.
#define PIX(A,B,Cc,D, I, DW, HV) {                                            \
    const int d = (int)(((DW) >> sh) & 3u);                                   \
    const float num = Cc[(I)+2];                                              \
    const float g0 = (d==0) ? Cc[(I)]   : ((d==2) ? A[(I)+2] : A[(I)+3]);     \
    const float g1 = (d==0) ? Cc[(I)+1] : B[(I)+2];                           \
    const float g2 = (d & 1) ? Cc[(I)+1] : num;                               \
    const float g3 = (d==0) ? Cc[(I)+3] : ((d==2) ? D[(I)+2] : D[(I)]);       \
    const float den = ((g0 + g1) + g2) + g3;                                  \
    const float nn = ((HV) && wvm[(I)]) ? num : 0.f;                          \
    acc += nn * fast_rcp(den); }

#define ROW(A,B,Cc,D, DQ, S) {                                                \
    const int gh = gh0 + (S);                                                 \
    const bool hv = (gh >= 2) && (gh < Hn-2);                                 \
    PIX(A,B,Cc,D, 0, (DQ).x, hv)                                              \
    PIX(A,B,Cc,D, 1, (DQ).y, hv)                                              \
    PIX(A,B,Cc,D, 2, (DQ).z, hv)                                              \
    PIX(A,B,Cc,D, 3, (DQ).w, hv) }

  LDROW(p0, r0-2)
  LDROW(p1, r0-1)
  LDROW(p2, r0+0)
  LDROW(p3, r0+1)
  ROW(p0,p1,p2,p3, dq0, 0)
  LDROW(p0, r0+2)
  ROW(p1,p2,p3,p0, dq1, 1)
  LDROW(p1, r0+3)
  ROW(p2,p3,p0,p1, dq2, 2)
  LDROW(p2, r0+4)
  ROW(p3,p0,p1,p2, dq3, 3)

#undef ROW
#undef PIX
#undef LDROW

  // ---- reduce: wave shuffle -> LDS -> one atomic per block into 256 slots ----
  const int lane = tid & 63;
  const int wq   = tid >> 6;
  #pragma unroll
  for (int off = 32; off > 0; off >>= 1)
    acc += __shfl_down(acc, off);
  if (lane == 0) wsum[wq] = acc;
  __syncthreads();
  if (tid == 0) {
    float s = 0.f;
    #pragma unroll
    for (int q = 0; q < NT/64; ++q) s += wsum[q];
    atomicAdd(&slots[(bz << 2) | (blockIdx.x & 3)], s);
    // release our slot-add, then bump the done counter (device scope)
    __threadfence();
    u32 prev = __hip_atomic_fetch_add(done_counter, 1u,
                                      __ATOMIC_ACQ_REL, __HIP_MEMORY_SCOPE_AGENT);
    lastFlag = (prev == (u32)(NMS_NBLK - 1)) ? 1 : 0;
  }
  __syncthreads();

  // last-finishing block: final 256 -> 1 reduction, write d_out
  if (lastFlag && tid < 64) {
    __threadfence();  // acquire side
    float s = 0.f;
    #pragma unroll
    for (int q = 0; q < 4; ++q)
      s += __hip_atomic_load(&slots[tid + 64*q],
                             __ATOMIC_RELAXED, __HIP_MEMORY_SCOPE_AGENT);
    #pragma unroll
    for (int off = 32; off > 0; off >>= 1)
      s += __shfl_down(s, off);
    if (tid == 0) *out = s;
  }
}

extern "C" void kernel_launch(void* const* d_in, const int* in_sizes, int n_in,
                              void* d_out, int out_size, void* d_ws, size_t ws_size,
                              hipStream_t stream) {
  (void)in_sizes; (void)n_in; (void)ws_size; (void)out_size;
  const float* pred   = (const float*)d_in[0];
  const int*   labels = (const int*)d_in[1];
  float* out = (float*)d_out;

  // d_ws layout: [0, 8 MB) u32 dir-map (fully overwritten by phase 1 each
  // call), then 256 float reduction slots, then 1 u32 done-counter.
  // Needs ws_size >= 8389636 B.
  u32*   dirs    = (u32*)d_ws;
  float* slots   = (float*)((char*)d_ws + (size_t)Bn*Hn*Wn*sizeof(u32));
  u32*   counter = (u32*)(slots + 256);

  dir_kernel<<<dim3(Wn/P1TW, Hn/P1TH, Bn), 256, 0, stream>>>(labels, dirs,
                                                             slots, counter);
  nms_sum_kernel<<<dim3(Wn/TW, Hn/TH, Bn*Cn), NT, 0, stream>>>(pred, dirs,
                                                               slots, counter,
                                                               out);
}

// Round 3
// 246.035 us; speedup vs baseline: 3.2756x; 3.2756x over previous
//
#include <hip/hip_runtime.h>

// StealNMSLoss for MI355X (gfx950).  Round 8: revert fence-bearing
// consolidation; keep fence-free slot-zeroing only.
//
// Round 7 post-mortem (806us, 3.2x REGRESSION): per-block __threadfence() +
// ACQ_REL agent-scope fetch_add in nms_sum -> device-scope L2
// writeback/invalidate per block x 8192 blocks.  Counters: nms_sum 630us,
// VALUBusy 4%, HBM 2% of peak, FETCH unchanged -> pure cache-flush stall +
// working-set eviction.  Lesson: a ~5us dispatch removal is never worth
// per-block device fences.
//
// Round 8 = round 6 kernel (247.9us, verified) with ONE safe change kept:
// dir_kernel block (0,0,0) zeroes the 256 reduction slots (plain stores;
// kernel-boundary coherence makes them visible to nms_sum).  hipMemsetAsync
// dispatch removed: 4 dispatches -> 3.
//
// Phase 1 (dir_kernel): per (b,pixel) compute 2-bit NMS direction for ALL 16
//   classes from the label map only; pack into u32/pixel dir-map in d_ws.
// Phase 2 (nms_sum_kernel): per (b,c,tile) stage exp(pred) tile in LDS; each
//   thread owns a 4-col x 4-row pixel patch; rolling 4-row register window,
//   14x ds_read_b128 per 16 pixels; per-pixel denominator = 6 cndmask + 3
//   adds; acc += num * rcp(den).
// Phase 3 (reduce_ws_kernel): 256 slots -> scalar.
//
// Math notes (bit-exact vs reference, rounds 1-7):
//  - Composed Sobel-of-Sobel on one-hot mask = exact integer stencils /64:
//      gxx = [1,4,6,4,1]_h (x) [1,0,-2,0,1]_w / 64
//      gxy = [-1,-2,0,2,1]_h (x) [-1,-2,0,2,1]_w / 64
//      gyy = [1,0,-2,0,1]_h (x) [1,4,6,4,1]_w / 64
//  - dir classification in exact integers (|gxx|,|gyy| <= 32): tan(pi/10)
//    lies between Farey neighbors 10/31, 1/3 -> t1 = (100|gyy| > 33|gxx|);
//    tan(3pi/10) between 11/8, 40/29 -> t2 = (1000|gyy| > 1377|gxx|).
//    gxx==0 (den=eps>0) and gyy==0 cases verified to match the float path.
//    ng = (gyy<0) ^ (gxy>0) ^ (gxx<0).
//  - Only interior [2,H-2) x [2,W-2) contributes; dirs 1,3 share the
//    anti-diagonal denominator (same offset set).
//  - Gather element positions relative to pixel (row r, col x), ascending
//    offset order and add association as rounds 5-7:
//      dir0 (horiz): (r,x-2) (r,x-1) (r,x) (r,x+1)
//      dir2 (vert):  (r-2,x) (r-1,x) (r,x) (r+1,x)
//      dir1/3:       (r-2,x+1) (r-1,x) (r,x-1) (r+1,x-2)
//    den = ((g0+g1)+g2)+g3, acc += nn * rcp(den) — unchanged numerics.

#define Bn 4
#define Cn 16
#define Hn 512
#define Wn 1024

typedef unsigned long long u64;
typedef unsigned int u32;
typedef float f4u __attribute__((ext_vector_type(4), aligned(4)));
typedef int   i4u __attribute__((ext_vector_type(4), aligned(4)));

static __device__ __forceinline__ float fast_rcp(float x) {
#if __has_builtin(__builtin_amdgcn_rcpf)
  return __builtin_amdgcn_rcpf(x);
#else
  return 1.0f / x;
#endif
}

// ======================= Phase 1: direction map =======================
// Tile 128w x 8h, 256 threads = 32 tcols x 8 rows; thread owns 4 adjacent
// pixels in one row.  SWAR over 8 pixel-byte-lanes per u64.

#define P1TW 128
#define P1TH 8
#define P1LW 132
#define P1LH 12

__global__ __launch_bounds__(256)
void dir_kernel(const int* __restrict__ labels, u32* __restrict__ dirs,
                float* __restrict__ slots)
{
  __shared__ unsigned char labt[P1LH][P1LW];

  const int w0 = blockIdx.x * P1TW;
  const int h0 = blockIdx.y * P1TH;
  const int b  = blockIdx.z;
  const int tid = threadIdx.x;

  // zero the reduction slots (replaces hipMemsetAsync dispatch); plain
  // stores — kernel-boundary coherence makes them visible to nms_sum.
  if (blockIdx.x == 0 && blockIdx.y == 0 && blockIdx.z == 0)
    slots[tid] = 0.f;

  const int* lbase = labels + (size_t)b * (Hn*Wn);
  const bool interior = (h0 >= 2) && (h0 + P1TH + 2 <= Hn) &&
                        (w0 >= 2) && (w0 + P1TW + 2 <= Wn);
  if (interior) {
    const int* lb = lbase + (size_t)(h0-2)*Wn + (w0-2);
    for (int i = tid; i < P1LH*33; i += 256) {
      int row = i / 33, c4 = (i - row*33) * 4;
      i4u L = *(const i4u*)(lb + row*Wn + c4);
      *(u32*)&labt[row][c4] =
          (u32)L.x | ((u32)L.y << 8) | ((u32)L.z << 16) | ((u32)L.w << 24);
    }
  } else {
    for (int i = tid; i < P1LH*33; i += 256) {
      int row = i / 33, c4 = (i - row*33) * 4;
      int gh = min(max(h0-2+row, 0), Hn-1);
      const int* lr = lbase + gh*Wn;
      u32 v = 0;
      #pragma unroll
      for (int k = 0; k < 4; ++k) {
        int gw = min(max(w0-2+c4+k, 0), Wn-1);
        v |= (u32)(lr[gw] & 0xff) << (8*k);
      }
      *(u32*)&labt[row][c4] = v;
    }
  }
  __syncthreads();

  const int tcol = tid & 31;
  const int trow = tid >> 5;

  // 5 window rows x 8 byte-cols (pixels at bytes 2..5 <-> gw = w0+4*tcol+0..3)
  u64 W[5];
  #pragma unroll
  for (int r = 0; r < 5; ++r) {
    const u32* lp = (const u32*)&labt[trow + r][0];
    u64 lo = lp[tcol];
    u64 hi = lp[tcol + 1];
    W[r] = lo | (hi << 32);
  }

  u32 pack[4] = {0u, 0u, 0u, 0u};

  #pragma unroll 1
  for (int c = 0; c < 16; ++c) {
    const u64 crep = 0x0101010101010101ULL * (u32)c;
    u64 m[5];
    #pragma unroll
    for (int r = 0; r < 5; ++r) {
      u64 x = W[r] ^ crep;
      m[r] = ((0x8080808080808080ULL - x) & 0x8080808080808080ULL) >> 7;
    }
    // vertical packed sums (pixel-byte lanes), all biases byte-safe:
    u64 t  = m[1] + m[3];
    u64 VA = m[0] + m[4] + (t << 2) + (m[2] << 2) + (m[2] << 1);          // [0,16]
    u64 VB = ((m[3] << 1) + m[4] + 0x0303030303030303ULL)
             - (m[0] + (m[1] << 1));                                       // [0,6]
    u64 VC = (m[0] + m[4] + 0x0202020202020202ULL) - (m[2] << 1);          // [0,4]
    // horizontal combine; result bytes k=0..3 = this thread's 4 pixels
    u64 gxxp = (VA + (VA >> 32) + 0x4040404040404040ULL) - ((VA >> 16) << 1);
    u64 q1   = (VC >> 8) + (VC >> 24);
    u64 w16  = VC >> 16;
    u64 gyyp = (VC + (VC >> 32)) + (q1 << 2) + (w16 << 2) + (w16 << 1);
    u64 gxyp = (((VB >> 24) << 1) + (VB >> 32) + 0x2020202020202020ULL)
             - (VB + ((VB >> 8) << 1));

    u32 gxxl = (u32)gxxp, gyyl = (u32)gyyp, gxyl = (u32)gxyp;
    #pragma unroll
    for (int k = 0; k < 4; ++k) {
      int gxx = (int)((gxxl >> (8*k)) & 0xffu) - 64;   // [-32,32]
      int gyy = (int)((gyyl >> (8*k)) & 0xffu) - 32;   // [-32,32]
      int gxyb = (int)((gxyl >> (8*k)) & 0xffu);       // >32 <=> gxy>0
      int ax = gxx < 0 ? -gxx : gxx;
      int ay = gyy < 0 ? -gyy : gyy;
      // __mul24: full-rate v_mul_u32_u24 (v_mul_lo_u32 is quarter-rate)
      int t1 = (__mul24(ay, 100)  > __mul24(ax, 33))   ? 1 : 0;
      int t2 = (__mul24(ay, 1000) > __mul24(ax, 1377)) ? 1 : 0;
      int rb = t1 + t2;
      bool ng = ((gyy < 0) != (gxyb > 32)) != (gxx < 0);
      int dir = ng ? ((rb == 2) ? 3 : 0) : rb;
      pack[k] |= (u32)dir << (2*c);
    }
  }

  const int gh = h0 + trow;
  u32* drow = dirs + ((size_t)b*Hn + gh)*Wn + (w0 + 4*tcol);
  *(uint4*)drow = make_uint4(pack[0], pack[1], pack[2], pack[3]);
}

// ======================= Phase 2: exp / denom sum =======================

#define TW 128
#define TH 32
#define LW 132
#define LH 36
#define NT 256

__global__ __launch_bounds__(NT)
void nms_sum_kernel(const float* __restrict__ pred,
                    const u32* __restrict__ dirs,
                    float* __restrict__ slots)
{
  __shared__ float ext[LH*LW];
  __shared__ float wsum[NT/64];

  const int w0 = blockIdx.x * TW;
  const int h0 = blockIdx.y * TH;
  const int bz = blockIdx.z;
  const int b  = bz >> 4;
  const int c  = bz & 15;
  const int tid = threadIdx.x;

  // compute-phase mapping: 256 threads = 8 row-groups x 32 col-groups;
  // thread owns a 4-col x 4-row pixel patch.
  const int tc  = tid & 31;
  const int rg  = tid >> 5;
  const int x0  = 4*tc;         // tile col of patch left edge
  const int r0  = 4*rg;         // tile row of patch top edge
  const int gw0 = w0 + x0;
  const int gh0 = h0 + r0;

  // ---- prefetch this thread's 16 dir words (issued before the barrier;
  //      dirs plane is 8 MB, reused by 16 class-blocks -> L2/L3 hits) ----
  const u32* dbase = dirs + (size_t)b*Hn*Wn + (size_t)gh0*Wn + gw0;
  const uint4 dq0 = *(const uint4*)(dbase);
  const uint4 dq1 = *(const uint4*)(dbase + Wn);
  const uint4 dq2 = *(const uint4*)(dbase + 2*(size_t)Wn);
  const uint4 dq3 = *(const uint4*)(dbase + 3*(size_t)Wn);

  // ---- stage exp tile ----
  const float* plane = pred + (size_t)(b*Cn + c) * (size_t)(Hn*Wn);
  const bool interior = (h0 >= 2) && (h0 + TH + 2 <= Hn) &&
                        (w0 >= 2) && (w0 + TW + 2 <= Wn);
  if (interior) {
    const float* pb = plane + (size_t)(h0-2)*Wn + (w0-2);
    for (int i = tid; i < LH*33; i += NT) {
      int row = i / 33, c4 = (i - row*33) * 4;
      f4u p = *(const f4u*)(pb + row*Wn + c4);
      float4 e;
      e.x = __expf(p.x); e.y = __expf(p.y); e.z = __expf(p.z); e.w = __expf(p.w);
      *(float4*)&ext[row*LW + c4] = e;
    }
  } else {
    for (int i = tid; i < LH*(LW/2); i += NT) {
      int row = i / (LW/2);
      int col = (i - row*(LW/2)) * 2;
      int gh = min(max(h0-2+row, 0), Hn-1);
      int ga = min(max(w0-2+col,   0), Wn-1);
      int gb = min(max(w0-1+col,   0), Wn-1);
      const float* prow = plane + gh*Wn;
      *(float2*)&ext[row*LW+col] = make_float2(__expf(prow[ga]), __expf(prow[gb]));
    }
  }
  __syncthreads();

  const u32 sh = 2u * (u32)c;

  // per-thread column validity, hoisted out of the row loop
  const bool wvm[4] = { (gw0+0 >= 2) && (gw0+0 < Wn-2),
                        (gw0+1 >= 2) && (gw0+1 < Wn-2),
                        (gw0+2 >= 2) && (gw0+2 < Wn-2),
                        (gw0+3 >= 2) && (gw0+3 < Wn-2) };

  // rolling 4-row register window: each row covers cols x0-2 .. x0+5.
  // LDS element index of (tile row t, col x0-2) = (t+2)*LW + x0 (16B-aligned).
  float p0[8], p1[8], p2[8], p3[8];

#define LDROW(P, TR) { const int _a = ((TR)+2)*LW + x0;                       \
    const f4u _lo = *(const f4u*)&ext[_a];                                    \
    const f4u _hi = *(const f4u*)&ext[_a + 4];                                \
    P[0]=_lo.x; P[1]=_lo.y; P[2]=_lo.z; P[3]=_lo.w;                           \
    P[4]=_hi.x; P[5]=_hi.y; P[6]=_hi.z; P[7]=_hi.w; }

  float acc = 0.f;

  // A = row r-2, B = row r-1, Cc = row r (pixel row), D = row r+1.
  // Pixel i sits at window element i+2.  Selects keep the ascending
  // offset order and add association exactly.
#define PIX(A,B,Cc,D, I, DW, HV) {                                            \
    const int d = (int)(((DW) >> sh) & 3u);                                   \
    const float num = Cc[(I)+2];                                              \
    const float g0 = (d==0) ? Cc[(I)]   : ((d==2) ? A[(I)+2] : A[(I)+3]);     \
    const float g1 = (d==0) ? Cc[(I)+1] : B[(I)+2];                           \
    const float g2 = (d & 1) ? Cc[(I)+1] : num;                               \
    const float g3 = (d==0) ? Cc[(I)+3] : ((d==2) ? D[(I)+2] : D[(I)]);       \
    const float den = ((g0 + g1) + g2) + g3;                                  \
    const float nn = ((HV) && wvm[(I)]) ? num : 0.f;                          \
    acc += nn * fast_rcp(den); }

#define ROW(A,B,Cc,D, DQ, S) {                                                \
    const int gh = gh0 + (S);                                                 \
    const bool hv = (gh >= 2) && (gh < Hn-2);                                 \
    PIX(A,B,Cc,D, 0, (DQ).x, hv)                                              \
    PIX(A,B,Cc,D, 1, (DQ).y, hv)                                              \
    PIX(A,B,Cc,D, 2, (DQ).z, hv)                                              \
    PIX(A,B,Cc,D, 3, (DQ).w, hv) }

  LDROW(p0, r0-2)
  LDROW(p1, r0-1)
  LDROW(p2, r0+0)
  LDROW(p3, r0+1)
  ROW(p0,p1,p2,p3, dq0, 0)
  LDROW(p0, r0+2)
  ROW(p1,p2,p3,p0, dq1, 1)
  LDROW(p1, r0+3)
  ROW(p2,p3,p0,p1, dq2, 2)
  LDROW(p2, r0+4)
  ROW(p3,p0,p1,p2, dq3, 3)

#undef ROW
#undef PIX
#undef LDROW

  // ---- reduce: wave shuffle -> LDS -> one atomic per block into 256 slots ----
  const int lane = tid & 63;
  const int wq   = tid >> 6;
  #pragma unroll
  for (int off = 32; off > 0; off >>= 1)
    acc += __shfl_down(acc, off);
  if (lane == 0) wsum[wq] = acc;
  __syncthreads();
  if (tid == 0) {
    float s = 0.f;
    #pragma unroll
    for (int q = 0; q < NT/64; ++q) s += wsum[q];
    atomicAdd(&slots[(bz << 2) | (blockIdx.x & 3)], s);
  }
}

__global__ __launch_bounds__(64)
void reduce_ws_kernel(const float* __restrict__ slots, float* __restrict__ out)
{
  const int l = threadIdx.x;
  float s = (slots[l] + slots[l + 64]) + (slots[l + 128] + slots[l + 192]);
  #pragma unroll
  for (int off = 32; off > 0; off >>= 1)
    s += __shfl_down(s, off);
  if (l == 0) *out = s;
}

extern "C" void kernel_launch(void* const* d_in, const int* in_sizes, int n_in,
                              void* d_out, int out_size, void* d_ws, size_t ws_size,
                              hipStream_t stream) {
  (void)in_sizes; (void)n_in; (void)ws_size; (void)out_size;
  const float* pred   = (const float*)d_in[0];
  const int*   labels = (const int*)d_in[1];
  float* out = (float*)d_out;

  // d_ws layout: [0, 8 MB) u32 dir-map (fully overwritten by phase 1 each
  // call), then 256 float reduction slots.  Needs ws_size >= 8389632 B.
  u32*   dirs  = (u32*)d_ws;
  float* slots = (float*)((char*)d_ws + (size_t)Bn*Hn*Wn*sizeof(u32));

  dir_kernel<<<dim3(Wn/P1TW, Hn/P1TH, Bn), 256, 0, stream>>>(labels, dirs, slots);
  nms_sum_kernel<<<dim3(Wn/TW, Hn/TH, Bn*Cn), NT, 0, stream>>>(pred, dirs, slots);
  reduce_ws_kernel<<<1, 64, 0, stream>>>(slots, out);
}